// Round 3
// baseline (284.730 us; speedup 1.0000x reference)
//
#include <hip/hip_runtime.h>

typedef _Float16 f16;
typedef __attribute__((ext_vector_type(4))) _Float16 f16x4;
typedef __attribute__((ext_vector_type(8))) _Float16 f16x8;
typedef __attribute__((ext_vector_type(4))) float f32x4;

constexpr int BATCH  = 4096;
constexpr int SEQ    = 512;
constexpr int HID    = 64;
constexpr int EMB_N4 = 50257 * 64 / 4;   // 804112 float4 groups in emb
constexpr float LOG2E2 = 2.8853900817779268f;   // 2*log2(e), folded into W/bias

// Only the gfx950-verified K32 shape is used anywhere in this file.
#define MFMA_K32(a, b, c) __builtin_amdgcn_mfma_f32_16x16x32_f16(a, b, c, 0, 0, 0)

// ---- Prep: emb fp32 -> fp16 (RNE); W_ih/W_hh -> fp16 pre-scaled by 2*log2e;
// zero BN acc. fp16 (2^-11) replaces bf16 (2^-9): emb rounding was the
// dominant error term in the bf16 version, so no hi/lo split is needed.
__global__ __launch_bounds__(256) void prep_kernel(
    const float4* __restrict__ emb4, const float* __restrict__ Wih,
    const float* __restrict__ Whh, f16x4* __restrict__ emb_f4,
    f16* __restrict__ wih_f, f16* __restrict__ whh_f, float* __restrict__ bn_acc)
{
  int gid = blockIdx.x * 256 + threadIdx.x;
  if (gid < EMB_N4) {
    float4 v = emb4[gid];
    f16x4 o = {(f16)v.x, (f16)v.y, (f16)v.z, (f16)v.w};
    emb_f4[gid] = o;
  } else if (gid < EMB_N4 + 1024) {
    int i0 = (gid - EMB_N4) * 4;
    #pragma unroll
    for (int k = 0; k < 4; ++k) {
      int i = i0 + k;
      wih_f[i] = (f16)(Wih[i] * LOG2E2);
      whh_f[i] = (f16)(Whh[i] * LOG2E2);
    }
  } else if (gid < EMB_N4 + 1024 + 128) {
    bn_acc[gid - (EMB_N4 + 1024)] = 0.f;   // ws is poisoned 0xAA every call
  }
}

// ---- Kernel 1: fused embedding-gather + input projection + tanh-RNN scan.
// ONE 64-lane wave per 16-row chain (256 blocks x 64 thr -> 1 chain/CU).
// No LDS, no barriers. Swapped product D = W * h^T with a PERMUTED K
// ordering on the recurrence so only K32 MFMAs are needed:
//   kappa(half; j=8q+e) = 16*(2*half + (e>>2)) + 4q + (e&3)
// Under kappa, the B-fragment of K-chunk `half` is exactly
// concat(hB[2*half], hB[2*half+1]) -- the D-tile register quads the lane
// already holds from the previous step (D layout: lane 16q+n, reg r ->
// feat 16f+4q+r, batch n). The A-fragment is the matching concat of two
// contiguous f16x4 slices of W_hh's row. h never leaves registers.
// emb gathers keep the 4-step-deep rotating register prefetch (covers
// ~900-cyc HBM/L3 latency); they are B-operands (xe^T) of K32 MFMAs in
// natural K order.
__global__ __launch_bounds__(64, 1) void rnn_scan_kernel(
    const int* __restrict__ xx, const f16* __restrict__ emb,
    const f16* __restrict__ wih, const f16* __restrict__ whh,
    const float* __restrict__ b_ih, const float* __restrict__ b_hh,
    float* __restrict__ hT /* [HID][BATCH] */, float* __restrict__ bn_acc)
{
  const int L = threadIdx.x;       // 0..63
  const int n = L & 15;            // batch col within tile / W row within tile
  const int q = L >> 4;            // k-group
  const int R0 = blockIdx.x << 4;  // first batch row of this chain

  // A-fragments (constant, per-lane):
  //  W_ih[f][half]: natural K order, lane holds W[16f+n][32*half+8q+e], e=0..7
  //  W_hh[f][half]: permuted K order, elements 0..3 = W[16f+n][32*half+4q+e],
  //                 elements 4..7 = W[16f+n][32*half+16+4q+e]
  f16x8 Wi[4][2], Wp[4][2];
  f32x4 bias[4];
  #pragma unroll
  for (int f = 0; f < 4; ++f) {
    const f16* wr = whh + (16 * f + n) * 64;
    #pragma unroll
    for (int h = 0; h < 2; ++h) {
      f16x4 lo = *(const f16x4*)(wr + 32 * h + 4 * q);
      f16x4 hi = *(const f16x4*)(wr + 32 * h + 16 + 4 * q);
      Wp[f][h] = __builtin_shufflevector(lo, hi, 0, 1, 2, 3, 4, 5, 6, 7);
    }
    const f16* wi = wih + (16 * f + n) * 64;
    Wi[f][0] = *(const f16x8*)(wi + 8 * q);
    Wi[f][1] = *(const f16x8*)(wi + 32 + 8 * q);
    // C-layout: lane 16q+n reg r -> feat 16f+4q+r (same for all n)
    float4 bi = *(const float4*)(b_ih + 16 * f + 4 * q);
    float4 bh = *(const float4*)(b_hh + 16 * f + 4 * q);
    f32x4 b = {(bi.x + bh.x) * LOG2E2, (bi.y + bh.y) * LOG2E2,
               (bi.z + bh.z) * LOG2E2, (bi.w + bh.w) * LOG2E2};
    bias[f] = b;
  }

  // h state as next-step B-fragments (permuted-K): hB01 = tiles {0,1},
  // hB23 = tiles {2,3}. h0 = 0.
  f16x8 hB01 = {0, 0, 0, 0, 0, 0, 0, 0};
  f16x8 hB23 = {0, 0, 0, 0, 0, 0, 0, 0};

  // idx stream: int4 = 4 steps. K1 always holds steps 4(t+1)..4(t+1)+3.
  // All 4 q-groups load identical x addresses (L1 broadcast, harmless).
  const int4* x4 = (const int4*)(xx + (R0 + n) * SEQ);
  int4 K1 = x4[1];

  // emb prefetch slots: slot u holds step 4t+u's B-fragments (distance 4).
  f16x8 e0[4], e1[4];
  {
    int4 K0 = x4[0];
    const int id0[4] = {K0.x, K0.y, K0.z, K0.w};
    #pragma unroll
    for (int u = 0; u < 4; ++u) {
      const f16* eb = emb + (long)id0[u] * 64 + 8 * q;
      e0[u] = *(const f16x8*)(eb);
      e1[u] = *(const f16x8*)(eb + 32);
    }
  }

  for (int t = 0; t < SEQ / 4; ++t) {
    int4 K2 = x4[(t + 2 < SEQ / 4) ? t + 2 : SEQ / 4 - 1];  // clamped; dup loads harmless
    const int nid[4] = {K1.x, K1.y, K1.z, K1.w};            // idx for steps 4t+4+u
    const bool lastt = (t == SEQ / 4 - 1);

    #pragma unroll
    for (int u = 0; u < 4; ++u) {
      // input projection: D_f = bias_f + W_ih[f] * xe^T   (8x K32 MFMA,
      // independent of h -> issue first, overlaps the recurrence chain)
      f32x4 D0 = MFMA_K32(Wi[0][0], e0[u], bias[0]);
      f32x4 D1 = MFMA_K32(Wi[1][0], e0[u], bias[1]);
      f32x4 D2 = MFMA_K32(Wi[2][0], e0[u], bias[2]);
      f32x4 D3 = MFMA_K32(Wi[3][0], e0[u], bias[3]);
      D0 = MFMA_K32(Wi[0][1], e1[u], D0);
      D1 = MFMA_K32(Wi[1][1], e1[u], D1);
      D2 = MFMA_K32(Wi[2][1], e1[u], D2);
      D3 = MFMA_K32(Wi[3][1], e1[u], D3);

      // refill slot u with step s+4 (stays in flight across 4 steps)
      {
        const f16* eb = emb + (long)nid[u] * 64 + 8 * q;
        e0[u] = *(const f16x8*)(eb);
        e1[u] = *(const f16x8*)(eb + 32);
      }

      // recurrence: D_f += W_hh[f] * h^T, permuted-K K32 (8 MFMAs).
      // chunk 0 = feats of tiles {0,1}; chunk 1 = feats of tiles {2,3}.
      D0 = MFMA_K32(Wp[0][0], hB01, D0);
      D1 = MFMA_K32(Wp[1][0], hB01, D1);
      D2 = MFMA_K32(Wp[2][0], hB01, D2);
      D3 = MFMA_K32(Wp[3][0], hB01, D3);
      D0 = MFMA_K32(Wp[0][1], hB23, D0);
      D1 = MFMA_K32(Wp[1][1], hB23, D1);
      D2 = MFMA_K32(Wp[2][1], hB23, D2);
      D3 = MFMA_K32(Wp[3][1], hB23, D3);

      // tanh from pre-scaled activation: tanh(v) = 1 - 2/(1 + 2^(2log2e*v));
      // exact saturation at +-1. Output tiles become next step's B-fragments.
      float th[4][4];
      #pragma unroll
      for (int r = 0; r < 4; ++r) {
        float e0f = __builtin_amdgcn_exp2f(D0[r]);
        float e1f = __builtin_amdgcn_exp2f(D1[r]);
        float e2f = __builtin_amdgcn_exp2f(D2[r]);
        float e3f = __builtin_amdgcn_exp2f(D3[r]);
        th[0][r] = fmaf(-2.0f, __builtin_amdgcn_rcpf(e0f + 1.0f), 1.0f);
        th[1][r] = fmaf(-2.0f, __builtin_amdgcn_rcpf(e1f + 1.0f), 1.0f);
        th[2][r] = fmaf(-2.0f, __builtin_amdgcn_rcpf(e2f + 1.0f), 1.0f);
        th[3][r] = fmaf(-2.0f, __builtin_amdgcn_rcpf(e3f + 1.0f), 1.0f);
        hB01[r]     = (f16)th[0][r];
        hB01[4 + r] = (f16)th[1][r];
        hB23[r]     = (f16)th[2][r];
        hB23[4 + r] = (f16)th[3][r];
      }

      if (lastt && u == 3) {   // epilogue: h_n out + BN partial sums
        #pragma unroll
        for (int f = 0; f < 4; ++f) {
          #pragma unroll
          for (int r = 0; r < 4; ++r) {
            float v = th[f][r];
            const int feat = 16 * f + 4 * q + r;
            hT[feat * BATCH + R0 + n] = v;     // coalesced over n
            float s1 = v, s2 = v * v;
            // reduce over batch (n = lanes 0..15 within each q-group)
            s1 += __shfl_xor(s1, 1, 64);  s2 += __shfl_xor(s2, 1, 64);
            s1 += __shfl_xor(s1, 2, 64);  s2 += __shfl_xor(s2, 2, 64);
            s1 += __shfl_xor(s1, 4, 64);  s2 += __shfl_xor(s2, 4, 64);
            s1 += __shfl_xor(s1, 8, 64);  s2 += __shfl_xor(s2, 8, 64);
            if (n == 0) {
              atomicAdd(bn_acc + feat, s1);
              atomicAdd(bn_acc + 64 + feat, s2);
            }
          }
        }
      }
    }
    K1 = K2;
  }
}

// ---- Kernel 2: BN fold (from accumulated sums) + logits GEMV. fp32 out.
__global__ __launch_bounds__(256) void head_kernel(
    const float* __restrict__ hT, const float* __restrict__ bn_acc,
    const float* __restrict__ gamma, const float* __restrict__ beta,
    const float* __restrict__ Wfc, const float* __restrict__ bfc,
    float* __restrict__ out)
{
  __shared__ float sc[64], sh[64];
  const int tid = threadIdx.x;
  if (tid < 64) {
    float mean = bn_acc[tid] * (1.0f / BATCH);
    float var  = bn_acc[64 + tid] * (1.0f / BATCH) - mean * mean;  // biased
    float inv  = rsqrtf(var + 1e-5f);
    float s    = gamma[tid] * inv;
    sc[tid] = s;
    sh[tid] = beta[tid] - mean * s;
  }
  __syncthreads();
  const int b = blockIdx.x * 256 + tid;
  float acc[5];
  #pragma unroll
  for (int c = 0; c < 5; ++c) acc[c] = bfc[c];
  for (int j = 0; j < HID; ++j) {
    float hv  = hT[j * BATCH + b];                 // coalesced across lanes
    float hat = fmaf(hv, sc[j], sh[j]);
    #pragma unroll
    for (int c = 0; c < 5; ++c) acc[c] = fmaf(hat, Wfc[c * 64 + j], acc[c]);
  }
  #pragma unroll
  for (int c = 0; c < 5; ++c) out[b * 5 + c] = acc[c];
}

extern "C" void kernel_launch(void* const* d_in, const int* in_sizes, int n_in,
                              void* d_out, int out_size, void* d_ws, size_t ws_size,
                              hipStream_t stream)
{
  const int*   x     = (const int*)d_in[0];
  const float* emb   = (const float*)d_in[1];
  const float* W_ih  = (const float*)d_in[2];
  const float* W_hh  = (const float*)d_in[3];
  const float* b_ih  = (const float*)d_in[4];
  const float* b_hh  = (const float*)d_in[5];
  const float* gamma = (const float*)d_in[6];
  const float* beta  = (const float*)d_in[7];
  const float* W_fc  = (const float*)d_in[8];
  const float* b_fc  = (const float*)d_in[9];

  char* ws = (char*)d_ws;
  float* hT     = (float*)ws;                 // [64][4096] fp32, 1 MB
  float* bn_acc = (float*)(ws + 1048576);     // [2][64] fp32 atomics
  f16*   emb_f  = (f16*)(ws + 1049088);       // [50257][64] f16, 6.43 MB
  f16*   wih_f  = (f16*)(ws + 7481984);       // [64][64] f16 (pre-scaled)
  f16*   whh_f  = (f16*)(ws + 7490176);       // [64][64] f16 (pre-scaled)

  const int prep_items = EMB_N4 + 1024 + 128;
  prep_kernel<<<dim3((prep_items + 255) / 256), dim3(256), 0, stream>>>(
      (const float4*)emb, W_ih, W_hh, (f16x4*)emb_f, wih_f, whh_f, bn_acc);
  rnn_scan_kernel<<<dim3(BATCH / 16), dim3(64), 0, stream>>>(
      x, emb_f, wih_f, whh_f, b_ih, b_hh, hT, bn_acc);
  head_kernel<<<dim3(BATCH / 256), dim3(256), 0, stream>>>(
      hT, bn_acc, gamma, beta, W_fc, b_fc, (float*)d_out);
}